// Round 2
// baseline (163.288 us; speedup 1.0000x reference)
//
#include <hip/hip_runtime.h>
#include <hip/hip_bf16.h>

#define EPS 1e-3f

// ---- ws layout (float offsets). Total 643088 floats = ~2.57 MB ----
#define OFF_PGAP   0         // 65536  : per-(block,channel) gap partial sums
#define OFF_QB     65536     // 1024   : q  [4][256] (channel attention)
#define OFF_KB     66560     // 1024   : k
#define OFF_VB     67584     // 1024   : v
#define OFF_A      68608     // 1024   : per-channel affine scale A[b][c]
#define OFF_BIAS   69632     // 16     : folded qkv bias [4][3]
#define OFF_QS     69648     // 16384  : spatial q  [4][4096]
#define OFF_KS     86032     // 16384  : spatial k
#define OFF_VS     102416    // 16384  : spatial v
#define OFF_PART   118800    // 524288 : attention partials [4][4096][8] float4(den,num,m,0)

// K1: gap partial sums. 256 blocks (b*64+chunk) x 256 threads, one channel per thread.
__global__ __launch_bounds__(256) void k_gap(const float* __restrict__ x,
                                             float* __restrict__ pgap) {
    int blk = blockIdx.x;            // 0..255 ; pixel base = blk*64
    int t = threadIdx.x;             // 0..255 ; channel
    const float* xp = x + (size_t)blk * (64 * 256) + t;
    float s = 0.f;
    #pragma unroll 8
    for (int p = 0; p < 64; ++p) s += xp[(size_t)p * 256];
    pgap[blk * 256 + t] = s;
}

// K2a: gap reduce + CA-BN + q/k/v = gn @ {wq,wk,wv}. 4 blocks (one per batch) x 256.
__global__ __launch_bounds__(256) void k_stage_a(
    const float* __restrict__ pgap,
    const float* __restrict__ cag, const float* __restrict__ cab,
    const float* __restrict__ cam, const float* __restrict__ cav,
    const float* __restrict__ wq, const float* __restrict__ wk,
    const float* __restrict__ wv,
    float* __restrict__ qb, float* __restrict__ kb, float* __restrict__ vb)
{
    __shared__ float gn[256];
    int b = blockIdx.x, t = threadIdx.x;
    float sc = cag[t] * rsqrtf(cav[t] + EPS);
    float ofs = cab[t] - cam[t] * sc;
    float s = 0.f;
    for (int k = 0; k < 64; ++k) s += pgap[(b * 64 + k) * 256 + t];
    gn[t] = (s * (1.0f / 4096.0f)) * sc + ofs;
    __syncthreads();
    float aq = 0.f, ak = 0.f, av = 0.f;
    for (int i = 0; i < 256; ++i) {
        float g = gn[i];
        aq = fmaf(g, wq[i * 256 + t], aq);
        ak = fmaf(g, wk[i * 256 + t], ak);
        av = fmaf(g, wv[i * 256 + t], av);
    }
    qb[b * 256 + t] = aq; kb[b * 256 + t] = ak; vb[b * 256 + t] = av;
}

// K2b: channel attention + sigmoid + 10th-percentile mask + fold A/bias. 4 blocks x 256.
__global__ __launch_bounds__(256) void k_stage_b(
    const float* __restrict__ qb, const float* __restrict__ kb, const float* __restrict__ vb,
    const float* __restrict__ wp,
    const float* __restrict__ bng, const float* __restrict__ bnb,
    const float* __restrict__ bnm, const float* __restrict__ bnv,
    const float* __restrict__ wqkv,
    float* __restrict__ Aout, float* __restrict__ biasOut)
{
    __shared__ float kk[256], vv[256], att[256], cm[256], Bc[256];
    __shared__ float t25, t26, thr;
    int b = blockIdx.x, t = threadIdx.x;
    kk[t] = kb[b * 256 + t]; vv[t] = vb[b * 256 + t];
    float a = qb[b * 256 + t];
    __syncthreads();
    // row t of channel attention (rank-1 logits a*k_j); exact row max -> exp args <= 0
    float mx = -1e30f;
    for (int j = 0; j < 256; ++j) mx = fmaxf(mx, a * kk[j]);
    float den = 0.f, num = 0.f;
    for (int j = 0; j < 256; ++j) {
        float e = __expf(a * kk[j] - mx);
        den += e; num = fmaf(e, vv[j], num);
    }
    att[t] = num / den;
    __syncthreads();
    // cmask = sigmoid(att @ wp)
    float ac = 0.f;
    for (int i = 0; i < 256; ++i) ac = fmaf(att[i], wp[i * 256 + t], ac);
    cm[t] = 1.0f / (1.0f + __expf(-ac));
    __syncthreads();
    // 10th percentile, linear: pos = 0.1*255 = 25.5 -> s[25] + 0.5*(s[26]-s[25])
    {
        float my = cm[t];
        int rank = 0;
        for (int j = 0; j < 256; ++j) {
            float o = cm[j];
            rank += (o < my) ? 1 : ((o == my && j < t) ? 1 : 0);
        }
        if (rank == 25) t25 = my;   // ranks are a permutation -> exactly one writer each
        if (rank == 26) t26 = my;
    }
    __syncthreads();
    if (t == 0) thr = t25 + 0.5f * (t26 - t25);
    __syncthreads();
    // co*pmask = x*A + B (per channel):  A=(1+cm)*s2*pm, B=(bnb-bnm*s2)*pm
    float s2 = bng[t] * rsqrtf(bnv[t] + EPS);
    float o2 = bnb[t] - bnm[t] * s2;
    float c = cm[t];
    float pm = (c > thr) ? c : 0.f;
    Aout[b * 256 + t] = (1.f + c) * s2 * pm;
    Bc[t] = o2 * pm;
    __syncthreads();
    if (t < 3) {
        float s3 = 0.f;
        for (int cch = 0; cch < 256; ++cch) s3 = fmaf(Bc[cch], wqkv[cch * 3 + t], s3);
        biasOut[b * 3 + t] = s3;
    }
}

// K3: qkv = (x*A + B) @ w_qkv. One wave per pixel, lane covers 4 channels. 1024 blocks x 256.
__global__ __launch_bounds__(256) void k_qkv(
    const float* __restrict__ x, const float* __restrict__ A,
    const float* __restrict__ wqkv, const float* __restrict__ bias,
    float* __restrict__ qs, float* __restrict__ ks, float* __restrict__ vs)
{
    int lane = threadIdx.x & 63;
    int wid = (blockIdx.x * 256 + threadIdx.x) >> 6;   // 0..4095 (wave-uniform)
    // lane handles channels 4*lane..4*lane+3; rows of wqkv are [C][3]
    float4 wA = *(const float4*)(wqkv + 12 * lane);      // r0: q k v | r1: q
    float4 wB = *(const float4*)(wqkv + 12 * lane + 4);  // r1: k v | r2: q k
    float4 wC = *(const float4*)(wqkv + 12 * lane + 8);  // r2: v | r3: q k v
    float w00 = wA.x, w01 = wA.y, w02 = wA.z;
    float w10 = wA.w, w11 = wB.x, w12 = wB.y;
    float w20 = wB.z, w21 = wB.w, w22 = wC.x;
    float w30 = wC.y, w31 = wC.z, w32 = wC.w;
    #pragma unroll
    for (int b = 0; b < 4; ++b) {
        int pix = b * 4096 + wid;
        float4 xv = *(const float4*)(x + (size_t)pix * 256 + 4 * lane);
        float4 A4 = *(const float4*)(A + b * 256 + 4 * lane);
        float t0 = xv.x * A4.x, t1 = xv.y * A4.y;
        float t2 = xv.z * A4.z, t3 = xv.w * A4.w;
        float q = t0 * w00 + t1 * w10 + t2 * w20 + t3 * w30;
        float k = t0 * w01 + t1 * w11 + t2 * w21 + t3 * w31;
        float v = t0 * w02 + t1 * w12 + t2 * w22 + t3 * w32;
        #pragma unroll
        for (int m = 1; m < 64; m <<= 1) {
            q += __shfl_xor(q, m, 64);
            k += __shfl_xor(k, m, 64);
            v += __shfl_xor(v, m, 64);
        }
        if (lane == 0) {
            qs[pix] = q + bias[b * 3 + 0];
            ks[pix] = k + bias[b * 3 + 1];
            vs[pix] = v + bias[b * 3 + 2];
        }
    }
}

// K4: spatial attention partials. 512 blocks = (b, 16 i-chunks, 8 j-chunks) x 256 threads.
// Rank-1 logits -> exact chunk-local row max is analytic; flash-combine in K5.
__global__ __launch_bounds__(256) void k_attn(
    const float* __restrict__ qs, const float* __restrict__ ks, const float* __restrict__ vs,
    float* __restrict__ part)
{
    __shared__ float2 skv[512];
    __shared__ float wmx[4], wmn[4];
    int blk = blockIdx.x;
    int b = blk >> 7, rem = blk & 127;
    int ic = rem >> 3, jc = rem & 7;
    int t = threadIdx.x;
    int base = b * 4096, jb = jc * 512;
    skv[t]       = make_float2(ks[base + jb + t],       vs[base + jb + t]);
    skv[t + 256] = make_float2(ks[base + jb + 256 + t], vs[base + jb + 256 + t]);
    __syncthreads();
    // chunk max/min of k
    float mx = fmaxf(skv[t].x, skv[t + 256].x);
    float mn = fminf(skv[t].x, skv[t + 256].x);
    #pragma unroll
    for (int m2 = 1; m2 < 64; m2 <<= 1) {
        mx = fmaxf(mx, __shfl_xor(mx, m2, 64));
        mn = fminf(mn, __shfl_xor(mn, m2, 64));
    }
    if ((t & 63) == 0) { wmx[t >> 6] = mx; wmn[t >> 6] = mn; }
    __syncthreads();
    mx = fmaxf(fmaxf(wmx[0], wmx[1]), fmaxf(wmx[2], wmx[3]));
    mn = fminf(fminf(wmn[0], wmn[1]), fminf(wmn[2], wmn[3]));

    int i = ic * 256 + t;
    float a = qs[base + i];
    float m = (a >= 0.f) ? a * mx : a * mn;   // exact chunk-local row max
    float den = 0.f, num = 0.f;
    #pragma unroll 4
    for (int j = 0; j < 512; ++j) {
        float2 kv = skv[j];                   // uniform addr -> LDS broadcast, conflict-free
        float e = __expf(a * kv.x - m);
        den += e;
        num = fmaf(e, kv.y, num);
    }
    ((float4*)part)[(size_t)(base + i) * 8 + jc] = make_float4(den, num, m, 0.f);
}

// K5: flash-combine 8 chunk partials, out = v + softmax@v. 64 blocks x 256.
__global__ __launch_bounds__(256) void k_out(
    const float* __restrict__ part, const float* __restrict__ vs,
    float* __restrict__ out)
{
    int t = blockIdx.x * 256 + threadIdx.x;  // 0..16383
    const float4* p4 = (const float4*)part + (size_t)t * 8;
    float4 p[8];
    #pragma unroll
    for (int c = 0; c < 8; ++c) p[c] = p4[c];
    float M = p[0].z;
    #pragma unroll
    for (int c = 1; c < 8; ++c) M = fmaxf(M, p[c].z);
    float den = 0.f, num = 0.f;
    #pragma unroll
    for (int c = 0; c < 8; ++c) {
        float sc = __expf(p[c].z - M);
        den = fmaf(p[c].x, sc, den);
        num = fmaf(p[c].y, sc, num);
    }
    out[t] = vs[t] + num / den;
}

extern "C" void kernel_launch(void* const* d_in, const int* in_sizes, int n_in,
                              void* d_out, int out_size, void* d_ws, size_t ws_size,
                              hipStream_t stream) {
    const float* x    = (const float*)d_in[0];
    const float* cag  = (const float*)d_in[1];
    const float* cab  = (const float*)d_in[2];
    const float* cam  = (const float*)d_in[3];
    const float* cav  = (const float*)d_in[4];
    const float* wq   = (const float*)d_in[5];
    const float* wk   = (const float*)d_in[6];
    const float* wv   = (const float*)d_in[7];
    const float* wp   = (const float*)d_in[8];
    const float* bng  = (const float*)d_in[9];
    const float* bnb  = (const float*)d_in[10];
    const float* bnm  = (const float*)d_in[11];
    const float* bnv  = (const float*)d_in[12];
    const float* wqkv = (const float*)d_in[13];

    float* ws   = (float*)d_ws;   // needs ~2.57 MB
    float* pgap = ws + OFF_PGAP;
    float* qb   = ws + OFF_QB;
    float* kb   = ws + OFF_KB;
    float* vb   = ws + OFF_VB;
    float* A    = ws + OFF_A;
    float* bias = ws + OFF_BIAS;
    float* qs   = ws + OFF_QS;
    float* ks   = ws + OFF_KS;
    float* vs   = ws + OFF_VS;
    float* part = ws + OFF_PART;

    k_gap<<<dim3(256), dim3(256), 0, stream>>>(x, pgap);
    k_stage_a<<<dim3(4), dim3(256), 0, stream>>>(pgap, cag, cab, cam, cav, wq, wk, wv,
                                                 qb, kb, vb);
    k_stage_b<<<dim3(4), dim3(256), 0, stream>>>(qb, kb, vb, wp, bng, bnb, bnm, bnv, wqkv,
                                                 A, bias);
    k_qkv<<<dim3(1024), dim3(256), 0, stream>>>(x, A, wqkv, bias, qs, ks, vs);
    k_attn<<<dim3(512), dim3(256), 0, stream>>>(qs, ks, vs, part);
    k_out<<<dim3(64), dim3(256), 0, stream>>>(part, vs, (float*)d_out);
}

// Round 3
// 147.627 us; speedup vs baseline: 1.1061x; 1.1061x over previous
//
#include <hip/hip_runtime.h>

#define EPS 1e-3f

// ---- ws layout (float offsets). Total ~640k floats = ~2.56 MB ----
#define OFF_PGAP   0         // 65536  : per-(block,channel) gap partial sums [256][256]
#define OFF_A      65536     // 1024   : per-channel affine scale A[b][c]
#define OFF_BIAS   66560     // 16     : folded qkv bias [4][3]
#define OFF_QS     66576     // 16384  : spatial q  [4][4096]
#define OFF_KS     82960     // 16384  : spatial k
#define OFF_VS     99344     // 16384  : spatial v
#define OFF_PART   115728    // 524288 : attention partials [4][4096][8] float4(den,num,m,0)

// K1: gap partial sums. 256 blocks (b*64+chunk) x 256 threads, one channel per thread.
__global__ __launch_bounds__(256) void k_gap(const float* __restrict__ x,
                                             float* __restrict__ pgap) {
    int blk = blockIdx.x;            // 0..255 ; pixel base = blk*64
    int t = threadIdx.x;             // channel
    const float* xp = x + (size_t)blk * (64 * 256) + t;
    float s = 0.f;
    #pragma unroll 16
    for (int p = 0; p < 64; ++p) s += xp[(size_t)p * 256];
    pgap[blk * 256 + t] = s;
}

// K2: ENTIRE middle stage. 4 blocks (one per batch) x 512 threads.
// Each 256-row weight dot is split h=0/1 over 128 rows with 16-deep load batching.
__global__ __launch_bounds__(512) void k_mid(
    const float* __restrict__ pgap,
    const float* __restrict__ cag, const float* __restrict__ cab,
    const float* __restrict__ cam, const float* __restrict__ cav,
    const float* __restrict__ wq, const float* __restrict__ wk,
    const float* __restrict__ wv, const float* __restrict__ wp,
    const float* __restrict__ bng, const float* __restrict__ bnb,
    const float* __restrict__ bnm, const float* __restrict__ bnv,
    const float* __restrict__ wqkv,
    float* __restrict__ Aout, float* __restrict__ biasOut)
{
    __shared__ float gn[256];
    __shared__ float sq[256], sk[256], sv[256], att[256], cm[256], Bc[256];
    __shared__ float part[3][2][256];
    __shared__ float red[512];
    __shared__ float t25, t26, thr;

    int b = blockIdx.x;
    int t = threadIdx.x;        // 0..511
    int c = t & 255;            // channel / output column
    int h = t >> 8;             // row-half 0/1 (wave-uniform)

    // ---- Phase A: gap reduce + CA BatchNorm -> gn[256] ----
    {
        const float* pg = pgap + (size_t)(b * 64 + h * 32) * 256 + c;
        float s = 0.f;
        #pragma unroll 16
        for (int k = 0; k < 32; ++k) s += pg[(size_t)k * 256];
        red[t] = s;
    }
    __syncthreads();
    if (h == 0) {
        float g = (red[c] + red[c + 256]) * (1.0f / 4096.0f);
        float sc = cag[c] * rsqrtf(cav[c] + EPS);
        gn[c] = g * sc + (cab[c] - cam[c] * sc);
    }
    __syncthreads();

    // ---- Phase B: q/k/v = gn @ {wq,wk,wv}; half h covers rows h*128..h*128+127 ----
    {
        int rbase = h * 128;
        float aq = 0.f, ak = 0.f, av = 0.f;
        const float* wqp = wq + (size_t)rbase * 256 + c;
        const float* wkp = wk + (size_t)rbase * 256 + c;
        const float* wvp = wv + (size_t)rbase * 256 + c;
        for (int r0 = 0; r0 < 128; r0 += 16) {
            float tq[16], tk[16], tv[16];
            #pragma unroll
            for (int u = 0; u < 16; ++u) tq[u] = wqp[(size_t)(r0 + u) * 256];
            #pragma unroll
            for (int u = 0; u < 16; ++u) tk[u] = wkp[(size_t)(r0 + u) * 256];
            #pragma unroll
            for (int u = 0; u < 16; ++u) tv[u] = wvp[(size_t)(r0 + u) * 256];
            #pragma unroll
            for (int u = 0; u < 16; ++u) {
                float g = gn[rbase + r0 + u];     // wave-uniform -> LDS broadcast
                aq = fmaf(g, tq[u], aq);
                ak = fmaf(g, tk[u], ak);
                av = fmaf(g, tv[u], av);
            }
        }
        part[0][h][c] = aq; part[1][h][c] = ak; part[2][h][c] = av;
    }
    __syncthreads();
    if (h == 0) {
        sq[c] = part[0][0][c] + part[0][1][c];
        sk[c] = part[1][0][c] + part[1][1][c];
        sv[c] = part[2][0][c] + part[2][1][c];
    }
    __syncthreads();

    // ---- Phase C: channel attention row c, rank-1 logits a*k_j; split j over halves ----
    {
        float a = sq[c];
        int jb = h * 128;
        float mx = -1e30f;
        #pragma unroll 8
        for (int j = 0; j < 128; ++j) mx = fmaxf(mx, a * sk[jb + j]);
        float den = 0.f, num = 0.f;
        #pragma unroll 4
        for (int j = 0; j < 128; ++j) {
            float e = __expf(a * sk[jb + j] - mx);
            den += e; num = fmaf(e, sv[jb + j], num);
        }
        part[0][h][c] = mx; part[1][h][c] = den; part[2][h][c] = num;
    }
    __syncthreads();
    if (h == 0) {
        float m0 = part[0][0][c], m1 = part[0][1][c];
        float M = fmaxf(m0, m1);
        float s0 = __expf(m0 - M), s1 = __expf(m1 - M);
        float den = part[1][0][c] * s0 + part[1][1][c] * s1;
        float num = part[2][0][c] * s0 + part[2][1][c] * s1;
        att[c] = num / den;
    }
    __syncthreads();

    // ---- Phase D: cm = sigmoid(att @ wp), rows split over halves ----
    {
        int rbase = h * 128;
        float ac = 0.f;
        const float* wpp = wp + (size_t)rbase * 256 + c;
        for (int r0 = 0; r0 < 128; r0 += 16) {
            float tw[16];
            #pragma unroll
            for (int u = 0; u < 16; ++u) tw[u] = wpp[(size_t)(r0 + u) * 256];
            #pragma unroll
            for (int u = 0; u < 16; ++u) ac = fmaf(att[rbase + r0 + u], tw[u], ac);
        }
        part[0][h][c] = ac;
    }
    __syncthreads();
    if (h == 0) {
        float ac = part[0][0][c] + part[0][1][c];
        cm[c] = 1.0f / (1.0f + __expf(-ac));
    }
    __syncthreads();

    // ---- Phase E: 10th percentile (linear): s[25] + 0.5*(s[26]-s[25]) ----
    if (h == 0) {
        float my = cm[c];
        int rank = 0;
        for (int j = 0; j < 256; ++j) {
            float o = cm[j];
            rank += (o < my) ? 1 : ((o == my && j < c) ? 1 : 0);
        }
        if (rank == 25) t25 = my;   // ranks form a permutation -> unique writers
        if (rank == 26) t26 = my;
    }
    __syncthreads();
    if (t == 0) thr = t25 + 0.5f * (t26 - t25);
    __syncthreads();

    // ---- Phase F: fold affine A,B; bias = B @ w_qkv ----
    if (h == 0) {
        float s2 = bng[c] * rsqrtf(bnv[c] + EPS);
        float o2 = bnb[c] - bnm[c] * s2;
        float cc = cm[c];
        float pm = (cc > thr) ? cc : 0.f;
        Aout[b * 256 + c] = (1.f + cc) * s2 * pm;
        Bc[c] = o2 * pm;
    }
    __syncthreads();
    if (t < 3) {
        float s3 = 0.f;
        for (int ch = 0; ch < 256; ++ch) s3 = fmaf(Bc[ch], wqkv[ch * 3 + t], s3);
        biasOut[b * 3 + t] = s3;
    }
}

// K3: qkv = (x*A + B) @ w_qkv. One wave per pixel, lane covers 4 channels. 1024 blocks x 256.
__global__ __launch_bounds__(256) void k_qkv(
    const float* __restrict__ x, const float* __restrict__ A,
    const float* __restrict__ wqkv, const float* __restrict__ bias,
    float* __restrict__ qs, float* __restrict__ ks, float* __restrict__ vs)
{
    int lane = threadIdx.x & 63;
    int wid = (blockIdx.x * 256 + threadIdx.x) >> 6;   // 0..4095 (wave-uniform)
    float4 wA = *(const float4*)(wqkv + 12 * lane);
    float4 wB = *(const float4*)(wqkv + 12 * lane + 4);
    float4 wC = *(const float4*)(wqkv + 12 * lane + 8);
    float w00 = wA.x, w01 = wA.y, w02 = wA.z;
    float w10 = wA.w, w11 = wB.x, w12 = wB.y;
    float w20 = wB.z, w21 = wB.w, w22 = wC.x;
    float w30 = wC.y, w31 = wC.z, w32 = wC.w;
    #pragma unroll
    for (int b = 0; b < 4; ++b) {
        int pix = b * 4096 + wid;
        float4 xv = *(const float4*)(x + (size_t)pix * 256 + 4 * lane);
        float4 A4 = *(const float4*)(A + b * 256 + 4 * lane);
        float t0 = xv.x * A4.x, t1 = xv.y * A4.y;
        float t2 = xv.z * A4.z, t3 = xv.w * A4.w;
        float q = t0 * w00 + t1 * w10 + t2 * w20 + t3 * w30;
        float k = t0 * w01 + t1 * w11 + t2 * w21 + t3 * w31;
        float v = t0 * w02 + t1 * w12 + t2 * w22 + t3 * w32;
        #pragma unroll
        for (int m = 1; m < 64; m <<= 1) {
            q += __shfl_xor(q, m, 64);
            k += __shfl_xor(k, m, 64);
            v += __shfl_xor(v, m, 64);
        }
        if (lane == 0) {
            qs[pix] = q + bias[b * 3 + 0];
            ks[pix] = k + bias[b * 3 + 1];
            vs[pix] = v + bias[b * 3 + 2];
        }
    }
}

// K4: spatial attention partials. 512 blocks = (b, 16 i-chunks, 8 j-chunks) x 256 threads.
__global__ __launch_bounds__(256) void k_attn(
    const float* __restrict__ qs, const float* __restrict__ ks, const float* __restrict__ vs,
    float* __restrict__ part)
{
    __shared__ float2 skv[512];
    __shared__ float wmx[4], wmn[4];
    int blk = blockIdx.x;
    int b = blk >> 7, rem = blk & 127;
    int ic = rem >> 3, jc = rem & 7;
    int t = threadIdx.x;
    int base = b * 4096, jb = jc * 512;
    skv[t]       = make_float2(ks[base + jb + t],       vs[base + jb + t]);
    skv[t + 256] = make_float2(ks[base + jb + 256 + t], vs[base + jb + 256 + t]);
    __syncthreads();
    float mx = fmaxf(skv[t].x, skv[t + 256].x);
    float mn = fminf(skv[t].x, skv[t + 256].x);
    #pragma unroll
    for (int m2 = 1; m2 < 64; m2 <<= 1) {
        mx = fmaxf(mx, __shfl_xor(mx, m2, 64));
        mn = fminf(mn, __shfl_xor(mn, m2, 64));
    }
    if ((t & 63) == 0) { wmx[t >> 6] = mx; wmn[t >> 6] = mn; }
    __syncthreads();
    mx = fmaxf(fmaxf(wmx[0], wmx[1]), fmaxf(wmx[2], wmx[3]));
    mn = fminf(fminf(wmn[0], wmn[1]), fminf(wmn[2], wmn[3]));

    int i = ic * 256 + t;
    float a = qs[base + i];
    float m = (a >= 0.f) ? a * mx : a * mn;   // exact chunk-local row max (rank-1 logits)
    float den = 0.f, num = 0.f;
    #pragma unroll 4
    for (int j = 0; j < 512; ++j) {
        float2 kv = skv[j];                    // uniform addr -> LDS broadcast
        float e = __expf(a * kv.x - m);
        den += e;
        num = fmaf(e, kv.y, num);
    }
    ((float4*)part)[(size_t)(base + i) * 8 + jc] = make_float4(den, num, m, 0.f);
}

// K5: flash-combine 8 chunk partials, out = v + softmax@v. 64 blocks x 256.
__global__ __launch_bounds__(256) void k_out(
    const float* __restrict__ part, const float* __restrict__ vs,
    float* __restrict__ out)
{
    int t = blockIdx.x * 256 + threadIdx.x;  // 0..16383
    const float4* p4 = (const float4*)part + (size_t)t * 8;
    float4 p[8];
    #pragma unroll
    for (int c = 0; c < 8; ++c) p[c] = p4[c];
    float M = p[0].z;
    #pragma unroll
    for (int c = 1; c < 8; ++c) M = fmaxf(M, p[c].z);
    float den = 0.f, num = 0.f;
    #pragma unroll
    for (int c = 0; c < 8; ++c) {
        float sc = __expf(p[c].z - M);
        den = fmaf(p[c].x, sc, den);
        num = fmaf(p[c].y, sc, num);
    }
    out[t] = vs[t] + num / den;
}

extern "C" void kernel_launch(void* const* d_in, const int* in_sizes, int n_in,
                              void* d_out, int out_size, void* d_ws, size_t ws_size,
                              hipStream_t stream) {
    const float* x    = (const float*)d_in[0];
    const float* cag  = (const float*)d_in[1];
    const float* cab  = (const float*)d_in[2];
    const float* cam  = (const float*)d_in[3];
    const float* cav  = (const float*)d_in[4];
    const float* wq   = (const float*)d_in[5];
    const float* wk   = (const float*)d_in[6];
    const float* wv   = (const float*)d_in[7];
    const float* wp   = (const float*)d_in[8];
    const float* bng  = (const float*)d_in[9];
    const float* bnb  = (const float*)d_in[10];
    const float* bnm  = (const float*)d_in[11];
    const float* bnv  = (const float*)d_in[12];
    const float* wqkv = (const float*)d_in[13];

    float* ws   = (float*)d_ws;
    float* pgap = ws + OFF_PGAP;
    float* A    = ws + OFF_A;
    float* bias = ws + OFF_BIAS;
    float* qs   = ws + OFF_QS;
    float* ks   = ws + OFF_KS;
    float* vs   = ws + OFF_VS;
    float* part = ws + OFF_PART;

    k_gap<<<dim3(256), dim3(256), 0, stream>>>(x, pgap);
    k_mid<<<dim3(4), dim3(512), 0, stream>>>(pgap, cag, cab, cam, cav, wq, wk, wv, wp,
                                             bng, bnb, bnm, bnv, wqkv, A, bias);
    k_qkv<<<dim3(1024), dim3(256), 0, stream>>>(x, A, wqkv, bias, qs, ks, vs);
    k_attn<<<dim3(512), dim3(256), 0, stream>>>(qs, ks, vs, part);
    k_out<<<dim3(64), dim3(256), 0, stream>>>(part, vs, (float*)d_out);
}

// Round 4
// 141.497 us; speedup vs baseline: 1.1540x; 1.0433x over previous
//
#include <hip/hip_runtime.h>

#define EPS 1e-3f

// ---- ws layout (float offsets) ----
#define OFF_PGAP   0         // 65536  : per-(block,channel) gap partial sums [256][256]
#define OFF_A      65536     // 1024   : per-channel affine scale A[b][c]
#define OFF_BIAS   66560     // 16     : folded qkv bias [4][3]
#define OFF_QS     66576     // 16384  : spatial q  [4][4096]
#define OFF_KS     82960     // 16384  : spatial k
#define OFF_VS     99344     // 16384  : spatial v
#define OFF_PART   115728    // 524288 : attention partials [4][4096][8] float4(den,num,m,0)

// K1: gap partial sums. 256 blocks (b*64+chunk) x 256 threads, one channel per thread.
__global__ __launch_bounds__(256) void k_gap(const float* __restrict__ x,
                                             float* __restrict__ pgap) {
    int blk = blockIdx.x;            // 0..255 ; pixel base = blk*64
    int t = threadIdx.x;             // channel
    const float* xp = x + (size_t)blk * (64 * 256) + t;
    float s = 0.f;
    #pragma unroll 16
    for (int p = 0; p < 64; ++p) s += xp[(size_t)p * 256];
    pgap[blk * 256 + t] = s;
}

// K2: entire middle stage. 4 blocks (one per batch) x 512 threads.
// All 256x256 weight matmuls use float4 column-loads (16B/lane, wave = 1KB row)
// with rows split 8 ways (cg = t&63 -> cols 4cg..4cg+3 ; rg = t>>6 -> rows 32rg..).
__global__ __launch_bounds__(512) void k_mid(
    const float* __restrict__ pgap,
    const float* __restrict__ cag, const float* __restrict__ cab,
    const float* __restrict__ cam, const float* __restrict__ cav,
    const float* __restrict__ wq, const float* __restrict__ wk,
    const float* __restrict__ wv, const float* __restrict__ wp,
    const float* __restrict__ bng, const float* __restrict__ bnb,
    const float* __restrict__ bnm, const float* __restrict__ bnv,
    const float* __restrict__ wqkv,
    float* __restrict__ Aout, float* __restrict__ biasOut)
{
    __shared__ float gn[256];
    __shared__ float sq[256], sk[256], sv[256], att[256], cm[256], Bc[256];
    __shared__ float red[6144];      // 24 KB scratch: [3 mats][8 rg][256 c]
    __shared__ float swqkv[768];
    __shared__ float t25, t26, thr;

    int b = blockIdx.x;
    int t = threadIdx.x;             // 0..511
    int cg = t & 63;                 // col group
    int rg = t >> 6;                 // row group (wave-uniform)
    int c4 = cg * 4;

    // stage wqkv early (Phase F consumer); coalesced, hidden behind Phase A/B
    if (t < 384) {
        swqkv[t] = wqkv[t];
        if (t < 384) swqkv[t + 384] = wqkv[t + 384];
    }

    // ---- Phase A: gap reduce (8-way row split, float4 cols) + CA BatchNorm ----
    {
        const float* pg = pgap + (size_t)(b * 64 + rg * 8) * 256 + c4;
        float4 s = make_float4(0.f, 0.f, 0.f, 0.f);
        #pragma unroll
        for (int u = 0; u < 8; ++u) {
            float4 v = *(const float4*)(pg + (size_t)u * 256);
            s.x += v.x; s.y += v.y; s.z += v.z; s.w += v.w;
        }
        *(float4*)(red + rg * 256 + c4) = s;
    }
    __syncthreads();
    if (t < 256) {
        float g = 0.f;
        #pragma unroll
        for (int r = 0; r < 8; ++r) g += red[r * 256 + t];
        g *= (1.0f / 4096.0f);
        float sc = cag[t] * rsqrtf(cav[t] + EPS);
        gn[t] = g * sc + (cab[t] - cam[t] * sc);
    }
    __syncthreads();

    // ---- Phase B: q/k/v = gn @ {wq,wk,wv} ----
    {
        int rbase = rg * 32;
        float4 aq = make_float4(0.f, 0.f, 0.f, 0.f);
        float4 ak = aq, av = aq;
        const float* wqp = wq + (size_t)rbase * 256 + c4;
        const float* wkp = wk + (size_t)rbase * 256 + c4;
        const float* wvp = wv + (size_t)rbase * 256 + c4;
        #pragma unroll 8
        for (int i = 0; i < 32; ++i) {
            float g = gn[rbase + i];                       // wave-uniform broadcast
            float4 w = *(const float4*)(wqp + (size_t)i * 256);
            aq.x = fmaf(g, w.x, aq.x); aq.y = fmaf(g, w.y, aq.y);
            aq.z = fmaf(g, w.z, aq.z); aq.w = fmaf(g, w.w, aq.w);
        }
        #pragma unroll 8
        for (int i = 0; i < 32; ++i) {
            float g = gn[rbase + i];
            float4 w = *(const float4*)(wkp + (size_t)i * 256);
            ak.x = fmaf(g, w.x, ak.x); ak.y = fmaf(g, w.y, ak.y);
            ak.z = fmaf(g, w.z, ak.z); ak.w = fmaf(g, w.w, ak.w);
        }
        #pragma unroll 8
        for (int i = 0; i < 32; ++i) {
            float g = gn[rbase + i];
            float4 w = *(const float4*)(wvp + (size_t)i * 256);
            av.x = fmaf(g, w.x, av.x); av.y = fmaf(g, w.y, av.y);
            av.z = fmaf(g, w.z, av.z); av.w = fmaf(g, w.w, av.w);
        }
        *(float4*)(red + (0 * 8 + rg) * 256 + c4) = aq;
        *(float4*)(red + (1 * 8 + rg) * 256 + c4) = ak;
        *(float4*)(red + (2 * 8 + rg) * 256 + c4) = av;
    }
    __syncthreads();
    {
        int m = t >> 8, c = t & 255;               // m=0: q ; m=1: k
        float s = 0.f;
        #pragma unroll
        for (int r = 0; r < 8; ++r) s += red[(m * 8 + r) * 256 + c];
        if (m == 0) sq[c] = s; else sk[c] = s;
        if (t < 256) {
            float s2 = 0.f;
            #pragma unroll
            for (int r = 0; r < 8; ++r) s2 += red[(2 * 8 + r) * 256 + t];
            sv[t] = s2;
        }
    }
    __syncthreads();

    // ---- Phase C: channel attention row c (rank-1 logits), j split over halves ----
    {
        int h = t >> 8, c = t & 255;
        float a = sq[c];
        int jb = h * 128;
        float mx = -1e30f;
        #pragma unroll 8
        for (int j = 0; j < 128; ++j) mx = fmaxf(mx, a * sk[jb + j]);
        float den = 0.f, num = 0.f;
        #pragma unroll 4
        for (int j = 0; j < 128; ++j) {
            float e = __expf(a * sk[jb + j] - mx);
            den += e; num = fmaf(e, sv[jb + j], num);
        }
        red[h * 256 + c] = mx;
        red[512 + h * 256 + c] = den;
        red[1024 + h * 256 + c] = num;
    }
    __syncthreads();
    if (t < 256) {
        float m0 = red[t], m1 = red[256 + t];
        float M = fmaxf(m0, m1);
        float s0 = __expf(m0 - M), s1 = __expf(m1 - M);
        float den = red[512 + t] * s0 + red[768 + t] * s1;
        float num = red[1024 + t] * s0 + red[1280 + t] * s1;
        att[t] = num / den;
    }
    __syncthreads();

    // ---- Phase D: cm = sigmoid(att @ wp), float4 cols, rows split 8 ways ----
    {
        int rbase = rg * 32;
        float4 ac = make_float4(0.f, 0.f, 0.f, 0.f);
        const float* wpp = wp + (size_t)rbase * 256 + c4;
        #pragma unroll 8
        for (int i = 0; i < 32; ++i) {
            float g = att[rbase + i];
            float4 w = *(const float4*)(wpp + (size_t)i * 256);
            ac.x = fmaf(g, w.x, ac.x); ac.y = fmaf(g, w.y, ac.y);
            ac.z = fmaf(g, w.z, ac.z); ac.w = fmaf(g, w.w, ac.w);
        }
        *(float4*)(red + rg * 256 + c4) = ac;
    }
    __syncthreads();
    if (t < 256) {
        float ac = 0.f;
        #pragma unroll
        for (int r = 0; r < 8; ++r) ac += red[r * 256 + t];
        cm[t] = 1.0f / (1.0f + __expf(-ac));
    }
    __syncthreads();

    // ---- Phase E: 10th percentile (linear): s[25] + 0.5*(s[26]-s[25]) ----
    if (t < 256) {
        float my = cm[t];
        int rank = 0;
        for (int j = 0; j < 256; ++j) {
            float o = cm[j];
            rank += (o < my) ? 1 : ((o == my && j < t) ? 1 : 0);
        }
        if (rank == 25) t25 = my;    // ranks form a permutation -> unique writers
        if (rank == 26) t26 = my;
    }
    __syncthreads();
    if (t == 0) thr = t25 + 0.5f * (t26 - t25);
    __syncthreads();

    // ---- Phase F: fold affine A,B; bias = B @ w_qkv (wqkv staged in LDS) ----
    if (t < 256) {
        float s2 = bng[t] * rsqrtf(bnv[t] + EPS);
        float o2 = bnb[t] - bnm[t] * s2;
        float cc = cm[t];
        float pm = (cc > thr) ? cc : 0.f;
        Aout[b * 256 + t] = (1.f + cc) * s2 * pm;
        Bc[t] = o2 * pm;
    }
    __syncthreads();
    if (t < 3) {
        float s3 = 0.f;
        for (int ch = 0; ch < 256; ++ch) s3 = fmaf(Bc[ch], swqkv[ch * 3 + t], s3);
        biasOut[b * 3 + t] = s3;
    }
}

// K3: qkv = (x*A + B) @ w_qkv. One wave per pixel, lane covers 4 channels. 1024 blocks x 256.
__global__ __launch_bounds__(256) void k_qkv(
    const float* __restrict__ x, const float* __restrict__ A,
    const float* __restrict__ wqkv, const float* __restrict__ bias,
    float* __restrict__ qs, float* __restrict__ ks, float* __restrict__ vs)
{
    int lane = threadIdx.x & 63;
    int wid = (blockIdx.x * 256 + threadIdx.x) >> 6;   // 0..4095 (wave-uniform)
    float4 wA = *(const float4*)(wqkv + 12 * lane);
    float4 wB = *(const float4*)(wqkv + 12 * lane + 4);
    float4 wC = *(const float4*)(wqkv + 12 * lane + 8);
    float w00 = wA.x, w01 = wA.y, w02 = wA.z;
    float w10 = wA.w, w11 = wB.x, w12 = wB.y;
    float w20 = wB.z, w21 = wB.w, w22 = wC.x;
    float w30 = wC.y, w31 = wC.z, w32 = wC.w;
    #pragma unroll
    for (int b = 0; b < 4; ++b) {
        int pix = b * 4096 + wid;
        float4 xv = *(const float4*)(x + (size_t)pix * 256 + 4 * lane);
        float4 A4 = *(const float4*)(A + b * 256 + 4 * lane);
        float t0 = xv.x * A4.x, t1 = xv.y * A4.y;
        float t2 = xv.z * A4.z, t3 = xv.w * A4.w;
        float q = t0 * w00 + t1 * w10 + t2 * w20 + t3 * w30;
        float k = t0 * w01 + t1 * w11 + t2 * w21 + t3 * w31;
        float v = t0 * w02 + t1 * w12 + t2 * w22 + t3 * w32;
        #pragma unroll
        for (int m = 1; m < 64; m <<= 1) {
            q += __shfl_xor(q, m, 64);
            k += __shfl_xor(k, m, 64);
            v += __shfl_xor(v, m, 64);
        }
        if (lane == 0) {
            qs[pix] = q + bias[b * 3 + 0];
            ks[pix] = k + bias[b * 3 + 1];
            vs[pix] = v + bias[b * 3 + 2];
        }
    }
}

// K4: spatial attention partials. 512 blocks = (b, 16 i-chunks, 8 j-chunks) x 256 threads.
// K/V packed as float4 pairs in LDS (one b128 broadcast covers 2 j's).
__global__ __launch_bounds__(256) void k_attn(
    const float* __restrict__ qs, const float* __restrict__ ks, const float* __restrict__ vs,
    float* __restrict__ part)
{
    __shared__ float4 skv4[256];     // (k[2j], v[2j], k[2j+1], v[2j+1])
    __shared__ float wmx[4], wmn[4];
    int blk = blockIdx.x;
    int b = blk >> 7, rem = blk & 127;
    int ic = rem >> 3, jc = rem & 7;
    int t = threadIdx.x;
    int base = b * 4096, jb = jc * 512;
    float2 kp = ((const float2*)(ks + base + jb))[t];
    float2 vp = ((const float2*)(vs + base + jb))[t];
    skv4[t] = make_float4(kp.x, vp.x, kp.y, vp.y);
    float mx = fmaxf(kp.x, kp.y);
    float mn = fminf(kp.x, kp.y);
    #pragma unroll
    for (int m2 = 1; m2 < 64; m2 <<= 1) {
        mx = fmaxf(mx, __shfl_xor(mx, m2, 64));
        mn = fminf(mn, __shfl_xor(mn, m2, 64));
    }
    if ((t & 63) == 0) { wmx[t >> 6] = mx; wmn[t >> 6] = mn; }
    __syncthreads();
    mx = fmaxf(fmaxf(wmx[0], wmx[1]), fmaxf(wmx[2], wmx[3]));
    mn = fminf(fminf(wmn[0], wmn[1]), fminf(wmn[2], wmn[3]));

    int i = ic * 256 + t;
    float a = qs[base + i];
    float m = (a >= 0.f) ? a * mx : a * mn;   // exact chunk-local row max (rank-1 logits)
    float den0 = 0.f, num0 = 0.f, den1 = 0.f, num1 = 0.f;
    #pragma unroll 4
    for (int j2 = 0; j2 < 256; ++j2) {
        float4 kv = skv4[j2];                 // uniform addr -> broadcast, conflict-free
        float e0 = __expf(a * kv.x - m);
        float e1 = __expf(a * kv.z - m);
        den0 += e0; num0 = fmaf(e0, kv.y, num0);
        den1 += e1; num1 = fmaf(e1, kv.w, num1);
    }
    ((float4*)part)[(size_t)(base + i) * 8 + jc] =
        make_float4(den0 + den1, num0 + num1, m, 0.f);
}

// K5: flash-combine 8 chunk partials, out = v + softmax@v. 64 blocks x 256.
__global__ __launch_bounds__(256) void k_out(
    const float* __restrict__ part, const float* __restrict__ vs,
    float* __restrict__ out)
{
    int t = blockIdx.x * 256 + threadIdx.x;  // 0..16383
    const float4* p4 = (const float4*)part + (size_t)t * 8;
    float4 p[8];
    #pragma unroll
    for (int c = 0; c < 8; ++c) p[c] = p4[c];
    float M = p[0].z;
    #pragma unroll
    for (int c = 1; c < 8; ++c) M = fmaxf(M, p[c].z);
    float den = 0.f, num = 0.f;
    #pragma unroll
    for (int c = 0; c < 8; ++c) {
        float sc = __expf(p[c].z - M);
        den = fmaf(p[c].x, sc, den);
        num = fmaf(p[c].y, sc, num);
    }
    out[t] = vs[t] + num / den;
}

extern "C" void kernel_launch(void* const* d_in, const int* in_sizes, int n_in,
                              void* d_out, int out_size, void* d_ws, size_t ws_size,
                              hipStream_t stream) {
    const float* x    = (const float*)d_in[0];
    const float* cag  = (const float*)d_in[1];
    const float* cab  = (const float*)d_in[2];
    const float* cam  = (const float*)d_in[3];
    const float* cav  = (const float*)d_in[4];
    const float* wq   = (const float*)d_in[5];
    const float* wk   = (const float*)d_in[6];
    const float* wv   = (const float*)d_in[7];
    const float* wp   = (const float*)d_in[8];
    const float* bng  = (const float*)d_in[9];
    const float* bnb  = (const float*)d_in[10];
    const float* bnm  = (const float*)d_in[11];
    const float* bnv  = (const float*)d_in[12];
    const float* wqkv = (const float*)d_in[13];

    float* ws   = (float*)d_ws;
    float* pgap = ws + OFF_PGAP;
    float* A    = ws + OFF_A;
    float* bias = ws + OFF_BIAS;
    float* qs   = ws + OFF_QS;
    float* ks   = ws + OFF_KS;
    float* vs   = ws + OFF_VS;
    float* part = ws + OFF_PART;

    k_gap<<<dim3(256), dim3(256), 0, stream>>>(x, pgap);
    k_mid<<<dim3(4), dim3(512), 0, stream>>>(pgap, cag, cab, cam, cav, wq, wk, wv, wp,
                                             bng, bnb, bnm, bnv, wqkv, A, bias);
    k_qkv<<<dim3(1024), dim3(256), 0, stream>>>(x, A, wqkv, bias, qs, ks, vs);
    k_attn<<<dim3(512), dim3(256), 0, stream>>>(qs, ks, vs, part);
    k_out<<<dim3(64), dim3(256), 0, stream>>>(part, vs, (float*)d_out);
}

// Round 5
// 139.261 us; speedup vs baseline: 1.1725x; 1.0161x over previous
//
#include <hip/hip_runtime.h>

#define EPS 1e-3f

// ---- ws layout (float offsets) ----
#define OFF_PGAP   0         // 65536  : per-(block,channel) gap partial sums [256][256]
#define OFF_A      65536     // 1024   : per-channel affine scale A[b][c]
#define OFF_BIAS   66560     // 16     : folded qkv bias [4][3]
#define OFF_QS     66576     // 16384  : spatial q  [4][4096]
#define OFF_KS     82960     // 16384  : spatial k
#define OFF_VS     99344     // 16384  : spatial v

// K1: gap partial sums. 256 blocks (b*64+chunk) x 256 threads, one channel per thread.
__global__ __launch_bounds__(256) void k_gap(const float* __restrict__ x,
                                             float* __restrict__ pgap) {
    int blk = blockIdx.x;            // 0..255 ; pixel base = blk*64
    int t = threadIdx.x;             // channel
    const float* xp = x + (size_t)blk * (64 * 256) + t;
    float s = 0.f;
    #pragma unroll 16
    for (int p = 0; p < 64; ++p) s += xp[(size_t)p * 256];
    pgap[blk * 256 + t] = s;
}

// K2: entire middle stage. 4 blocks (one per batch) x 512 threads.
// All 256x256 weight matmuls use float4 column-loads (16B/lane, wave = 1KB row)
// with rows split 8 ways (cg = t&63 -> cols 4cg..4cg+3 ; rg = t>>6 -> rows 32rg..).
__global__ __launch_bounds__(512) void k_mid(
    const float* __restrict__ pgap,
    const float* __restrict__ cag, const float* __restrict__ cab,
    const float* __restrict__ cam, const float* __restrict__ cav,
    const float* __restrict__ wq, const float* __restrict__ wk,
    const float* __restrict__ wv, const float* __restrict__ wp,
    const float* __restrict__ bng, const float* __restrict__ bnb,
    const float* __restrict__ bnm, const float* __restrict__ bnv,
    const float* __restrict__ wqkv,
    float* __restrict__ Aout, float* __restrict__ biasOut)
{
    __shared__ float gn[256];
    __shared__ float sq[256], sk[256], sv[256], att[256], cm[256], Bc[256];
    __shared__ float red[6144];      // 24 KB scratch: [3 mats][8 rg][256 c]
    __shared__ float swqkv[768];
    __shared__ float t25, t26, thr;

    int b = blockIdx.x;
    int t = threadIdx.x;             // 0..511
    int cg = t & 63;                 // col group
    int rg = t >> 6;                 // row group (wave-uniform)
    int c4 = cg * 4;

    // stage wqkv early (Phase F consumer); coalesced, hidden behind Phase A/B
    if (t < 384) {
        swqkv[t] = wqkv[t];
        swqkv[t + 384] = wqkv[t + 384];
    }

    // ---- Phase A: gap reduce (8-way row split, float4 cols) + CA BatchNorm ----
    {
        const float* pg = pgap + (size_t)(b * 64 + rg * 8) * 256 + c4;
        float4 s = make_float4(0.f, 0.f, 0.f, 0.f);
        #pragma unroll
        for (int u = 0; u < 8; ++u) {
            float4 v = *(const float4*)(pg + (size_t)u * 256);
            s.x += v.x; s.y += v.y; s.z += v.z; s.w += v.w;
        }
        *(float4*)(red + rg * 256 + c4) = s;
    }
    __syncthreads();
    if (t < 256) {
        float g = 0.f;
        #pragma unroll
        for (int r = 0; r < 8; ++r) g += red[r * 256 + t];
        g *= (1.0f / 4096.0f);
        float sc = cag[t] * rsqrtf(cav[t] + EPS);
        gn[t] = g * sc + (cab[t] - cam[t] * sc);
    }
    __syncthreads();

    // ---- Phase B: q/k/v = gn @ {wq,wk,wv} ----
    {
        int rbase = rg * 32;
        float4 aq = make_float4(0.f, 0.f, 0.f, 0.f);
        float4 ak = aq, av = aq;
        const float* wqp = wq + (size_t)rbase * 256 + c4;
        const float* wkp = wk + (size_t)rbase * 256 + c4;
        const float* wvp = wv + (size_t)rbase * 256 + c4;
        #pragma unroll 8
        for (int i = 0; i < 32; ++i) {
            float g = gn[rbase + i];                       // wave-uniform broadcast
            float4 w = *(const float4*)(wqp + (size_t)i * 256);
            aq.x = fmaf(g, w.x, aq.x); aq.y = fmaf(g, w.y, aq.y);
            aq.z = fmaf(g, w.z, aq.z); aq.w = fmaf(g, w.w, aq.w);
        }
        #pragma unroll 8
        for (int i = 0; i < 32; ++i) {
            float g = gn[rbase + i];
            float4 w = *(const float4*)(wkp + (size_t)i * 256);
            ak.x = fmaf(g, w.x, ak.x); ak.y = fmaf(g, w.y, ak.y);
            ak.z = fmaf(g, w.z, ak.z); ak.w = fmaf(g, w.w, ak.w);
        }
        #pragma unroll 8
        for (int i = 0; i < 32; ++i) {
            float g = gn[rbase + i];
            float4 w = *(const float4*)(wvp + (size_t)i * 256);
            av.x = fmaf(g, w.x, av.x); av.y = fmaf(g, w.y, av.y);
            av.z = fmaf(g, w.z, av.z); av.w = fmaf(g, w.w, av.w);
        }
        *(float4*)(red + (0 * 8 + rg) * 256 + c4) = aq;
        *(float4*)(red + (1 * 8 + rg) * 256 + c4) = ak;
        *(float4*)(red + (2 * 8 + rg) * 256 + c4) = av;
    }
    __syncthreads();
    {
        int m = t >> 8, c = t & 255;               // m=0: q ; m=1: k
        float s = 0.f;
        #pragma unroll
        for (int r = 0; r < 8; ++r) s += red[(m * 8 + r) * 256 + c];
        if (m == 0) sq[c] = s; else sk[c] = s;
        if (t < 256) {
            float s2 = 0.f;
            #pragma unroll
            for (int r = 0; r < 8; ++r) s2 += red[(2 * 8 + r) * 256 + t];
            sv[t] = s2;
        }
    }
    __syncthreads();

    // ---- Phase C: channel attention row c (rank-1 logits), j split over halves ----
    {
        int h = t >> 8, c = t & 255;
        float a = sq[c];
        int jb = h * 128;
        float mx = -1e30f;
        #pragma unroll 8
        for (int j = 0; j < 128; ++j) mx = fmaxf(mx, a * sk[jb + j]);
        float den = 0.f, num = 0.f;
        #pragma unroll 4
        for (int j = 0; j < 128; ++j) {
            float e = __expf(a * sk[jb + j] - mx);
            den += e; num = fmaf(e, sv[jb + j], num);
        }
        red[h * 256 + c] = mx;
        red[512 + h * 256 + c] = den;
        red[1024 + h * 256 + c] = num;
    }
    __syncthreads();
    if (t < 256) {
        float m0 = red[t], m1 = red[256 + t];
        float M = fmaxf(m0, m1);
        float s0 = __expf(m0 - M), s1 = __expf(m1 - M);
        float den = red[512 + t] * s0 + red[768 + t] * s1;
        float num = red[1024 + t] * s0 + red[1280 + t] * s1;
        att[t] = num / den;
    }
    __syncthreads();

    // ---- Phase D: cm = sigmoid(att @ wp), float4 cols, rows split 8 ways ----
    {
        int rbase = rg * 32;
        float4 ac = make_float4(0.f, 0.f, 0.f, 0.f);
        const float* wpp = wp + (size_t)rbase * 256 + c4;
        #pragma unroll 8
        for (int i = 0; i < 32; ++i) {
            float g = att[rbase + i];
            float4 w = *(const float4*)(wpp + (size_t)i * 256);
            ac.x = fmaf(g, w.x, ac.x); ac.y = fmaf(g, w.y, ac.y);
            ac.z = fmaf(g, w.z, ac.z); ac.w = fmaf(g, w.w, ac.w);
        }
        *(float4*)(red + rg * 256 + c4) = ac;
    }
    __syncthreads();
    if (t < 256) {
        float ac = 0.f;
        #pragma unroll
        for (int r = 0; r < 8; ++r) ac += red[r * 256 + t];
        cm[t] = 1.0f / (1.0f + __expf(-ac));
    }
    __syncthreads();

    // ---- Phase E: 10th percentile (linear): s[25] + 0.5*(s[26]-s[25]) ----
    if (t < 256) {
        float my = cm[t];
        int rank = 0;
        for (int j = 0; j < 256; ++j) {
            float o = cm[j];
            rank += (o < my) ? 1 : ((o == my && j < t) ? 1 : 0);
        }
        if (rank == 25) t25 = my;    // ranks form a permutation -> unique writers
        if (rank == 26) t26 = my;
    }
    __syncthreads();
    if (t == 0) thr = t25 + 0.5f * (t26 - t25);
    __syncthreads();

    // ---- Phase F: fold affine A,B; bias = B @ w_qkv (wqkv staged in LDS) ----
    if (t < 256) {
        float s2 = bng[t] * rsqrtf(bnv[t] + EPS);
        float o2 = bnb[t] - bnm[t] * s2;
        float cc = cm[t];
        float pm = (cc > thr) ? cc : 0.f;
        Aout[b * 256 + t] = (1.f + cc) * s2 * pm;
        Bc[t] = o2 * pm;
    }
    __syncthreads();
    if (t < 3) {
        float s3 = 0.f;
        for (int ch = 0; ch < 256; ++ch) s3 = fmaf(Bc[ch], swqkv[ch * 3 + t], s3);
        biasOut[b * 3 + t] = s3;
    }
}

// K3: qkv = (x*A + B) @ w_qkv. One wave per pixel, lane covers 4 channels. 1024 blocks x 256.
__global__ __launch_bounds__(256) void k_qkv(
    const float* __restrict__ x, const float* __restrict__ A,
    const float* __restrict__ wqkv, const float* __restrict__ bias,
    float* __restrict__ qs, float* __restrict__ ks, float* __restrict__ vs)
{
    int lane = threadIdx.x & 63;
    int wid = (blockIdx.x * 256 + threadIdx.x) >> 6;   // 0..4095 (wave-uniform)
    float4 wA = *(const float4*)(wqkv + 12 * lane);
    float4 wB = *(const float4*)(wqkv + 12 * lane + 4);
    float4 wC = *(const float4*)(wqkv + 12 * lane + 8);
    float w00 = wA.x, w01 = wA.y, w02 = wA.z;
    float w10 = wA.w, w11 = wB.x, w12 = wB.y;
    float w20 = wB.z, w21 = wB.w, w22 = wC.x;
    float w30 = wC.y, w31 = wC.z, w32 = wC.w;
    #pragma unroll
    for (int b = 0; b < 4; ++b) {
        int pix = b * 4096 + wid;
        float4 xv = *(const float4*)(x + (size_t)pix * 256 + 4 * lane);
        float4 A4 = *(const float4*)(A + b * 256 + 4 * lane);
        float t0 = xv.x * A4.x, t1 = xv.y * A4.y;
        float t2 = xv.z * A4.z, t3 = xv.w * A4.w;
        float q = t0 * w00 + t1 * w10 + t2 * w20 + t3 * w30;
        float k = t0 * w01 + t1 * w11 + t2 * w21 + t3 * w31;
        float v = t0 * w02 + t1 * w12 + t2 * w22 + t3 * w32;
        #pragma unroll
        for (int m = 1; m < 64; m <<= 1) {
            q += __shfl_xor(q, m, 64);
            k += __shfl_xor(k, m, 64);
            v += __shfl_xor(v, m, 64);
        }
        if (lane == 0) {
            qs[pix] = q + bias[b * 3 + 0];
            ks[pix] = k + bias[b * 3 + 1];
            vs[pix] = v + bias[b * 3 + 2];
        }
    }
}

// K4: fused spatial attention + output. 256 blocks = (b, 64 row-chunks) x 512 threads.
// Full batch K/V (32 KB) LDS-resident; global k-max/min -> exact row max, no flash
// combine; wave `sub` covers a 512-j slice (uniform LDS addr = broadcast); direct out.
__global__ __launch_bounds__(512) void k_attn2(
    const float* __restrict__ qs, const float* __restrict__ ks, const float* __restrict__ vs,
    float* __restrict__ out)
{
    __shared__ float4 skv[2048];          // (k0,v0,k1,v1) pairs for all 4096 j : 32 KB
    __shared__ float pden[8][64], pnum[8][64];
    __shared__ float rmax[8], rmin[8];
    int blk = blockIdx.x;                 // 256 = b(4) * ic(64)
    int b = blk >> 6, ic = blk & 63;
    int t = threadIdx.x;                  // 0..511
    int lane = t & 63, sub = t >> 6;      // sub = wave id (wave-uniform)
    int base = b * 4096;

    const float4* k4 = (const float4*)(ks + base);
    const float4* v4 = (const float4*)(vs + base);
    float kmx = -1e30f, kmn = 1e30f;
    #pragma unroll
    for (int u = 0; u < 2; ++u) {
        int i = t + u * 512;              // 0..1023 float4 rows
        float4 kk = k4[i], vv = v4[i];
        skv[i * 2]     = make_float4(kk.x, vv.x, kk.y, vv.y);
        skv[i * 2 + 1] = make_float4(kk.z, vv.z, kk.w, vv.w);
        kmx = fmaxf(kmx, fmaxf(fmaxf(kk.x, kk.y), fmaxf(kk.z, kk.w)));
        kmn = fminf(kmn, fminf(fminf(kk.x, kk.y), fminf(kk.z, kk.w)));
    }
    #pragma unroll
    for (int m2 = 1; m2 < 64; m2 <<= 1) {
        kmx = fmaxf(kmx, __shfl_xor(kmx, m2, 64));
        kmn = fminf(kmn, __shfl_xor(kmn, m2, 64));
    }
    if (lane == 0) { rmax[sub] = kmx; rmin[sub] = kmn; }
    __syncthreads();
    float mx = rmax[0], mn = rmin[0];
    #pragma unroll
    for (int s = 1; s < 8; ++s) { mx = fmaxf(mx, rmax[s]); mn = fminf(mn, rmin[s]); }

    int row = ic * 64 + lane;
    float a = qs[base + row];
    float m = (a >= 0.f) ? a * mx : a * mn;   // exact global row max (rank-1 logits)
    float den0 = 0.f, num0 = 0.f, den1 = 0.f, num1 = 0.f;
    const float4* sp = skv + sub * 256;       // this wave's 512-j slice
    #pragma unroll 4
    for (int j = 0; j < 256; ++j) {
        float4 kv = sp[j];                    // uniform addr -> broadcast, conflict-free
        float e0 = __expf(fmaf(a, kv.x, -m));
        float e1 = __expf(fmaf(a, kv.z, -m));
        den0 += e0; num0 = fmaf(e0, kv.y, num0);
        den1 += e1; num1 = fmaf(e1, kv.w, num1);
    }
    pden[sub][lane] = den0 + den1;
    pnum[sub][lane] = num0 + num1;
    __syncthreads();
    if (t < 64) {
        float den = 0.f, num = 0.f;
        #pragma unroll
        for (int s = 0; s < 8; ++s) { den += pden[s][t]; num += pnum[s][t]; }
        int r = ic * 64 + t;
        float vrow = (r & 1) ? skv[r >> 1].w : skv[r >> 1].y;   // v from LDS
        out[base + r] = vrow + num / den;
    }
}

extern "C" void kernel_launch(void* const* d_in, const int* in_sizes, int n_in,
                              void* d_out, int out_size, void* d_ws, size_t ws_size,
                              hipStream_t stream) {
    const float* x    = (const float*)d_in[0];
    const float* cag  = (const float*)d_in[1];
    const float* cab  = (const float*)d_in[2];
    const float* cam  = (const float*)d_in[3];
    const float* cav  = (const float*)d_in[4];
    const float* wq   = (const float*)d_in[5];
    const float* wk   = (const float*)d_in[6];
    const float* wv   = (const float*)d_in[7];
    const float* wp   = (const float*)d_in[8];
    const float* bng  = (const float*)d_in[9];
    const float* bnb  = (const float*)d_in[10];
    const float* bnm  = (const float*)d_in[11];
    const float* bnv  = (const float*)d_in[12];
    const float* wqkv = (const float*)d_in[13];

    float* ws   = (float*)d_ws;
    float* pgap = ws + OFF_PGAP;
    float* A    = ws + OFF_A;
    float* bias = ws + OFF_BIAS;
    float* qs   = ws + OFF_QS;
    float* ks   = ws + OFF_KS;
    float* vs   = ws + OFF_VS;

    k_gap<<<dim3(256), dim3(256), 0, stream>>>(x, pgap);
    k_mid<<<dim3(4), dim3(512), 0, stream>>>(pgap, cag, cab, cam, cav, wq, wk, wv, wp,
                                             bng, bnb, bnm, bnv, wqkv, A, bias);
    k_qkv<<<dim3(1024), dim3(256), 0, stream>>>(x, A, wqkv, bias, qs, ks, vs);
    k_attn2<<<dim3(256), dim3(512), 0, stream>>>(qs, ks, vs, (float*)d_out);
}